// Round 15
// baseline (199.773 us; speedup 1.0000x reference)
//
#include <hip/hip_runtime.h>
#include <hip/hip_bf16.h>
#include <hip/hip_fp8.h>

// SRU layer: LN+Wprep fused -> fused split GEMM (u: bf16; f/r: fp8 e4m3 BK=128
// k-interleaved) -> chunked scan (4 chains/thread).  L=2048, B=8, D=1024.

typedef unsigned short u16;
typedef unsigned char u8;
typedef __bf16 bf16x8 __attribute__((ext_vector_type(8)));
typedef float f32x4 __attribute__((ext_vector_type(4)));
typedef long longx2 __attribute__((ext_vector_type(2)));

#define L_DIM 2048
#define B_DIM 8
#define D_DIM 1024
#define M_DIM (L_DIM * B_DIM)   // 16384
#define K_DIM D_DIM             // 1024
#define N_DIM (3 * D_DIM)       // 3072
#define NCH 32
#define CLEN (L_DIM / NCH)      // 64
#define NT (K_DIM / 64)         // 16 bf16 K-tiles
#define NT8 (K_DIM / 128)       // 8 fp8 K-tiles

// GEMM LDS: A dbuf 2x32K @0, B dbuf 2x32K @65536, dummy 16K @131072
#define LDS_B 65536
#define LDS_DUMMY 131072
#define LDS_TOTAL 147456

__device__ __forceinline__ float bf2f(u16 h) {
    unsigned int u = ((unsigned int)h) << 16;
    float f;
    __builtin_memcpy(&f, &u, 4);
    return f;
}

__device__ __forceinline__ u16 f2bf(float f) {
    unsigned int u;
    __builtin_memcpy(&u, &f, 4);
    u = u + 0x7fff + ((u >> 16) & 1);   // RNE
    return (u16)(u >> 16);
}

__device__ __forceinline__ u8 f2e4(float v) {
    __hip_fp8_e4m3 t(v);   // OCP e4m3fn, RNE
    return (u8)t.__x;
}

// fp8 k-interleave: within each 128B K-block, byte for k goes to
// pos = ((kk>>1)*4 + lg)*16 + (kk&1)*8 + e   (kk=k>>5, lg=(k>>3)&3, e=k&7)
__device__ __forceinline__ int kperm(int klocal) {
    int kk = klocal >> 5, lg = (klocal >> 3) & 3, e = klocal & 7;
    return (((kk >> 1) * 4 + lg) << 4) + ((kk & 1) << 3) + e;
}

__device__ __forceinline__ void async16(void* lds, const void* g) {
    __builtin_amdgcn_global_load_lds(
        (const __attribute__((address_space(1))) void*)g,
        (__attribute__((address_space(3))) void*)lds, 16, 0, 0);
}

// ---------------- Fused LN + W-prep (independent work, one dispatch) ----------------
// blockIdx.x < M_DIM: LayerNorm row -> xn bf16, xq fp8 k-interleaved, (mu,rs).
// else: W 64x64 tile -> Wt bf16 (n<1024) or Wf8 fp8*64 k-interleaved (n>=1024).
__global__ __launch_bounds__(256) void lnwt_kernel(const float* __restrict__ x,
                                                   const float* __restrict__ gamma,
                                                   const float* __restrict__ beta,
                                                   const float* __restrict__ W,
                                                   u16* __restrict__ xn,
                                                   u8* __restrict__ xq,
                                                   float2* __restrict__ mrs,
                                                   u16* __restrict__ Wt,
                                                   u8* __restrict__ Wf8) {
    __shared__ float smem[64 * 65];
    int tid = threadIdx.x;
    if (blockIdx.x < M_DIM) {
        int row = blockIdx.x;
        const float4* xr = (const float4*)(x + (size_t)row * D_DIM);
        float4 v = xr[tid];
        float s = v.x + v.y + v.z + v.w;
        float q = v.x * v.x + v.y * v.y + v.z * v.z + v.w * v.w;
        #pragma unroll
        for (int off = 32; off; off >>= 1) {
            s += __shfl_down(s, off);
            q += __shfl_down(q, off);
        }
        int lane = tid & 63, wv = tid >> 6;
        if (lane == 0) { smem[wv] = s; smem[4 + wv] = q; }
        __syncthreads();
        s = smem[0] + smem[1] + smem[2] + smem[3];
        q = smem[4] + smem[5] + smem[6] + smem[7];
        float mu = s * (1.0f / D_DIM);
        float var = q * (1.0f / D_DIM) - mu * mu;
        float rs = rsqrtf(var + 1e-5f);
        if (tid == 0) mrs[row] = make_float2(mu, rs);
        float4 g = ((const float4*)gamma)[tid];
        float4 bt = ((const float4*)beta)[tid];
        float n0 = (v.x - mu) * rs * g.x + bt.x;
        float n1 = (v.y - mu) * rs * g.y + bt.y;
        float n2 = (v.z - mu) * rs * g.z + bt.z;
        float n3 = (v.w - mu) * rs * g.w + bt.w;
        ushort4 o;
        o.x = f2bf(n0); o.y = f2bf(n1); o.z = f2bf(n2); o.w = f2bf(n3);
        ((ushort4*)(xn + (size_t)row * D_DIM))[tid] = o;
        uchar4 o8;
        o8.x = f2e4(n0); o8.y = f2e4(n1); o8.z = f2e4(n2); o8.w = f2e4(n3);
        int k4 = tid * 4;
        int pos = (k4 & ~127) + kperm(k4 & 127);   // 4B-aligned (e in {0,4})
        *(uchar4*)(xq + (size_t)row * D_DIM + pos) = o8;
    } else {
        int wb = blockIdx.x - M_DIM;      // 0..767
        int k0 = (wb & 15) * 64;
        int n0 = (wb >> 4) * 64;
        int col = tid & 63;
        int rg4 = tid >> 6;
        float (*t)[65] = (float(*)[65])smem;
        #pragma unroll
        for (int j = 0; j < 16; ++j) {
            int r = rg4 * 16 + j;
            t[r][col] = W[(size_t)(k0 + r) * N_DIM + n0 + col];
        }
        __syncthreads();
        if (n0 < 1024) {
            #pragma unroll
            for (int j = 0; j < 16; ++j) {
                int nr = rg4 * 16 + j;
                Wt[(size_t)(n0 + nr) * K_DIM + k0 + col] = f2bf(t[col][nr]);
            }
        } else {
            #pragma unroll
            for (int j = 0; j < 16; ++j) {
                int nr = rg4 * 16 + j;
                int k = k0 + col;
                int pos = (k & ~127) + kperm(k & 127);
                Wf8[(size_t)(n0 - 1024 + nr) * K_DIM + pos] = f2e4(t[col][nr] * 64.0f);
            }
        }
    }
}

// ---------------- Fused GEMM: grid (64,12). y<4: bf16 u-path; y>=4: fp8 f/r-path ------
// R14 verbatim (103.5 us, MfmaUtil 41%, conflicts 0).
__global__ __launch_bounds__(512, 2) void gemm_fused(const u16* __restrict__ A,
                                                     const u16* __restrict__ Bt,
                                                     const u8* __restrict__ A8,
                                                     const u8* __restrict__ B8,
                                                     const float* __restrict__ bias,
                                                     u16* __restrict__ uo,
                                                     u16* __restrict__ fo,
                                                     u16* __restrict__ ro) {
    extern __shared__ char lds[];
    const int tid = threadIdx.x;
    const int wave = tid >> 6, lane = tid & 63;
    const int lm = lane & 15, lg = lane >> 4;
    const int wm = wave >> 2, wn = wave & 3;   // 2M x 4N
    const int m0 = blockIdx.x * 256;

#define PH_SYNC()                                                               \
    do { __builtin_amdgcn_s_barrier();                                          \
         asm volatile("s_waitcnt lgkmcnt(0)");                                  \
         __builtin_amdgcn_sched_barrier(0); } while (0)

    if (blockIdx.y < 4) {
        // ================= bf16 u-path =================
        const int n0 = blockIdx.y * 256;       // < 1024

        const int xk0 = ((0 | lg) ^ (lm & 7)) << 4;
        const int xk1 = ((4 | lg) ^ (lm & 7)) << 4;
        const char* pA0 = lds + (wm * 128 + lm) * 128 + xk0;
        const char* pA1 = lds + (wm * 128 + lm) * 128 + xk1;
        const char* pB0 = lds + LDS_B + (wn * 64 + lm) * 128 + xk0;
        const char* pB1 = lds + LDS_B + (wn * 64 + lm) * 128 + xk1;

        const int c1 = 512 + tid;
        const int r0 = tid >> 3, cc0 = (tid & 7) ^ (r0 & 7);
        const int r1 = c1 >> 3, cc1 = (c1 & 7) ^ (r1 & 7);
        const char* gA0 = (const char*)A + ((size_t)(m0 + r0) * K_DIM + cc0 * 8) * 2;
        const char* gA1 = (const char*)A + ((size_t)(m0 + r1) * K_DIM + cc1 * 8) * 2;
        const char* gB0 = (const char*)Bt + ((size_t)(n0 + r0) * K_DIM + cc0 * 8) * 2;
        const char* gB1 = (const char*)Bt + ((size_t)(n0 + r1) * K_DIM + cc1 * 8) * 2;
        char* dstW = lds + wave * 1024;

        f32x4 acc[8][4] = {};
        bf16x8 av[4], aw[4], bv0[4], bv1[4];

        auto stageA = [&](int t1, int h) {
            char* dst = (t1 < NT) ? (dstW + ((t1 & 1) << 15) + (h << 14))
                                  : (lds + LDS_DUMMY + wave * 1024);
            int ko = ((t1 & 15) << 7) + (h << 18);
            async16(dst,        gA0 + ko);
            async16(dst + 8192, gA1 + ko);
        };
        auto stageB = [&](int t2, int h) {
            char* dst = (t2 < NT) ? (dstW + LDS_B + ((t2 & 1) << 15) + (h << 14))
                                  : (lds + LDS_DUMMY + wave * 1024);
            int ko = ((t2 & 15) << 7) + (h << 18);
            async16(dst,        gB0 + ko);
            async16(dst + 8192, gB1 + ko);
        };

#define LDA(dst, pbase, bb, mf0)                                                \
    do { _Pragma("unroll")                                                      \
        for (int q = 0; q < 4; ++q)                                             \
            dst[q] = *(const bf16x8*)(pbase + (bb) * 32768 + ((mf0) + q) * 2048); \
    } while (0)

#define LDB(dst, pbase, bb)                                                     \
    do { _Pragma("unroll")                                                      \
        for (int nf = 0; nf < 4; ++nf)                                          \
            dst[nf] = *(const bf16x8*)(pbase + (bb) * 32768 + nf * 2048);       \
    } while (0)

#define MFMA16(r0q, afr, bfr)                                                   \
    do { _Pragma("unroll")                                                      \
        for (int q = 0; q < 4; ++q)                                             \
            _Pragma("unroll")                                                   \
            for (int nf = 0; nf < 4; ++nf)                                      \
                acc[(r0q) + q][nf] = __builtin_amdgcn_mfma_f32_16x16x32_bf16(   \
                    afr[q], bfr[nf], acc[(r0q) + q][nf], 0, 0, 0);              \
    } while (0)

#define TILE_BODY(t, bb)                                                        \
    do {                                                                        \
        LDA(av, pA0, bb, 0);                                                    \
        LDB(bv0, pB0, bb);                                                      \
        stageA((t) + 1, 0);                                                     \
        PH_SYNC();                                                              \
        __builtin_amdgcn_s_setprio(1);  MFMA16(0, av, bv0);                     \
        __builtin_amdgcn_s_setprio(0);  __builtin_amdgcn_s_barrier();           \
        LDA(av, pA1, bb, 0);                                                    \
        LDB(bv1, pB1, bb);                                                      \
        stageA((t) + 1, 1);                                                     \
        PH_SYNC();                                                              \
        __builtin_amdgcn_s_setprio(1);  MFMA16(0, av, bv1);                     \
        __builtin_amdgcn_s_setprio(0);  __builtin_amdgcn_s_barrier();           \
        LDA(aw, pA0, bb, 4);                                                    \
        stageB((t) + 2, 0);                                                     \
        PH_SYNC();                                                              \
        __builtin_amdgcn_s_setprio(1);  MFMA16(4, aw, bv0);                     \
        __builtin_amdgcn_s_setprio(0);  __builtin_amdgcn_s_barrier();           \
        LDA(aw, pA1, bb, 4);                                                    \
        stageB((t) + 2, 1);                                                     \
        PH_SYNC();                                                              \
        __builtin_amdgcn_s_setprio(1);  MFMA16(4, aw, bv1);                     \
        __builtin_amdgcn_s_setprio(0);                                          \
        asm volatile("s_waitcnt vmcnt(4)" ::: "memory");                        \
        __builtin_amdgcn_s_barrier();                                           \
    } while (0)

        stageA(0, 0); stageA(0, 1);
        stageB(0, 0); stageB(0, 1);
        stageB(1, 0); stageB(1, 1);
        asm volatile("s_waitcnt vmcnt(4)" ::: "memory");
        __builtin_amdgcn_s_barrier();

        for (int t = 0; t < NT; t += 2) {
            TILE_BODY(t, 0);
            TILE_BODY(t + 1, 1);
        }

        float bb4[4];
        #pragma unroll
        for (int nf = 0; nf < 4; ++nf) bb4[nf] = bias[n0 + wn * 64 + nf * 16 + lm];
        const int cmb = n0 + wn * 64 + lm;
        #pragma unroll
        for (int mf = 0; mf < 8; ++mf) {
            #pragma unroll
            for (int j = 0; j < 4; ++j) {
                int row = m0 + wm * 128 + mf * 16 + lg * 4 + j;
                u16* rp = uo + (size_t)row * D_DIM + cmb;
                #pragma unroll
                for (int nf = 0; nf < 4; ++nf)
                    rp[nf * 16] = f2bf(acc[mf][nf][j] + bb4[nf]);
            }
        }
#undef LDA
#undef LDB
#undef MFMA16
#undef TILE_BODY
    } else {
        // ================= fp8 f/r-path =================
        const int n0 = (blockIdx.y - 4) * 256;   // 0..2047 (f,r cols)

        const int xj0 = (((0 * 4 + lg) ^ (lm & 7)) << 4);   // kk-pair a=0
        const int xj1 = (((1 * 4 + lg) ^ (lm & 7)) << 4);   // kk-pair a=1
        const char* pA = lds + (wm * 128 + lm) * 128;
        const char* pB = lds + LDS_B + (wn * 64 + lm) * 128;

        const int c1 = 512 + tid;
        const int r0 = tid >> 3, cc0 = (tid & 7) ^ (r0 & 7);
        const int r1 = c1 >> 3, cc1 = (c1 & 7) ^ (r1 & 7);
        const char* gA0 = (const char*)A8 + (size_t)(m0 + r0) * K_DIM + cc0 * 16;
        const char* gA1 = (const char*)A8 + (size_t)(m0 + r1) * K_DIM + cc1 * 16;
        const char* gB0 = (const char*)B8 + (size_t)(n0 + r0) * K_DIM + cc0 * 16;
        const char* gB1 = (const char*)B8 + (size_t)(n0 + r1) * K_DIM + cc1 * 16;
        char* dstW = lds + wave * 1024;

        f32x4 acc[8][4] = {};
        longx2 av[8], bv01[4], bv23[4];

        auto stageA8 = [&](int t1, int h) {
            char* dst = (t1 < NT8) ? (dstW + ((t1 & 1) << 15) + (h << 14))
                                   : (lds + LDS_DUMMY + wave * 1024);
            int ko = ((t1 & 7) << 7) + (h << 17);
            async16(dst,        gA0 + ko);
            async16(dst + 8192, gA1 + ko);
        };
        auto stageB8 = [&](int t2, int h) {
            char* dst = (t2 < NT8) ? (dstW + LDS_B + ((t2 & 1) << 15) + (h << 14))
                                   : (lds + LDS_DUMMY + wave * 1024);
            int ko = ((t2 & 7) << 7) + (h << 17);
            async16(dst,        gB0 + ko);
            async16(dst + 8192, gB1 + ko);
        };

#define LDA8(xj, bb)                                                            \
    do { _Pragma("unroll")                                                      \
        for (int q = 0; q < 8; ++q)                                             \
            av[q] = *(const longx2*)(pA + (bb) * 32768 + q * 2048 + (xj));      \
    } while (0)

#define LDB8(dst, xj, bb)                                                       \
    do { _Pragma("unroll")                                                      \
        for (int nf = 0; nf < 4; ++nf)                                          \
            dst[nf] = *(const longx2*)(pB + (bb) * 32768 + nf * 2048 + (xj));   \
    } while (0)

#define MFMA32F8(bfr, h)                                                        \
    do { _Pragma("unroll")                                                      \
        for (int q = 0; q < 8; ++q)                                             \
            _Pragma("unroll")                                                   \
            for (int nf = 0; nf < 4; ++nf)                                      \
                acc[q][nf] = __builtin_amdgcn_mfma_f32_16x16x32_fp8_fp8(        \
                    av[q][h], bfr[nf][h], acc[q][nf], 0, 0, 0);                 \
    } while (0)

#define TILE_BODY8(t, bb)                                                       \
    do {                                                                        \
        LDA8(xj0, bb);                                                          \
        LDB8(bv01, xj0, bb);                                                    \
        stageA8((t) + 1, 0);                                                    \
        PH_SYNC();                                                              \
        __builtin_amdgcn_s_setprio(1);  MFMA32F8(bv01, 0);                      \
        __builtin_amdgcn_s_setprio(0);  __builtin_amdgcn_s_barrier();           \
        LDB8(bv23, xj1, bb);                                                    \
        stageA8((t) + 1, 1);                                                    \
        PH_SYNC();                                                              \
        __builtin_amdgcn_s_setprio(1);  MFMA32F8(bv01, 1);                      \
        __builtin_amdgcn_s_setprio(0);  __builtin_amdgcn_s_barrier();           \
        LDA8(xj1, bb);                                                          \
        stageB8((t) + 2, 0);                                                    \
        PH_SYNC();                                                              \
        __builtin_amdgcn_s_setprio(1);  MFMA32F8(bv23, 0);                      \
        __builtin_amdgcn_s_setprio(0);  __builtin_amdgcn_s_barrier();           \
        stageB8((t) + 2, 1);                                                    \
        __builtin_amdgcn_s_barrier();                                           \
        __builtin_amdgcn_s_setprio(1);  MFMA32F8(bv23, 1);                      \
        __builtin_amdgcn_s_setprio(0);                                          \
        asm volatile("s_waitcnt vmcnt(4)" ::: "memory");                        \
        __builtin_amdgcn_s_barrier();                                           \
    } while (0)

        stageA8(0, 0); stageA8(0, 1);
        stageB8(0, 0); stageB8(0, 1);
        stageB8(1, 0); stageB8(1, 1);
        asm volatile("s_waitcnt vmcnt(4)" ::: "memory");
        __builtin_amdgcn_s_barrier();

        for (int t = 0; t < NT8; t += 2) {
            TILE_BODY8(t, 0);
            TILE_BODY8(t + 1, 1);
        }

        int seg = n0 >> 10;   // 0 -> f, 1 -> r (block-uniform)
        u16* outp = seg ? ro : fo;
        float bb4[4];
        #pragma unroll
        for (int nf = 0; nf < 4; ++nf) bb4[nf] = bias[1024 + n0 + wn * 64 + nf * 16 + lm];
        const int cmb = (n0 + wn * 64 + lm) & 1023;
        #pragma unroll
        for (int mf = 0; mf < 8; ++mf) {
            #pragma unroll
            for (int j = 0; j < 4; ++j) {
                int row = m0 + wm * 128 + mf * 16 + lg * 4 + j;
                u16* rp = outp + (size_t)row * D_DIM + cmb;
                #pragma unroll
                for (int nf = 0; nf < 4; ++nf) {
                    float val = acc[mf][nf][j] * 0.015625f + bb4[nf];
                    rp[nf * 16] = f2bf(1.0f / (1.0f + __expf(-val)));
                }
            }
        }
#undef LDA8
#undef LDB8
#undef MFMA32F8
#undef TILE_BODY8
    }
#undef PH_SYNC
}

// ---------------- Scan phase 1: 4 chains/thread, ushort4 (8B/lane) loads ----------------
__global__ __launch_bounds__(256) void scan1_kernel(const u16* __restrict__ fg,
                                                    const u16* __restrict__ u,
                                                    float* __restrict__ Aa,
                                                    float* __restrict__ Ss) {
    int ch = blockIdx.x;
    int bd = (blockIdx.y * 256 + threadIdx.x) * 4;
    int b = bd >> 10, d = bd & 1023;
    float a0 = 1.f, a1 = 1.f, a2 = 1.f, a3 = 1.f;
    float s0 = 0.f, s1 = 0.f, s2 = 0.f, s3 = 0.f;
    for (int t = ch * CLEN; t < ch * CLEN + CLEN; ++t) {
        size_t idx = ((size_t)(t * B_DIM + b) << 10) + d;
        ushort4 f4 = *(const ushort4*)(fg + idx);
        ushort4 u4 = *(const ushort4*)(u + idx);
        float f0 = bf2f(f4.x), f1 = bf2f(f4.y), f2 = bf2f(f4.z), f3 = bf2f(f4.w);
        float v0 = bf2f(u4.x), v1 = bf2f(u4.y), v2 = bf2f(u4.z), v3 = bf2f(u4.w);
        s0 = f0 * s0 + (1.0f - f0) * v0;
        s1 = f1 * s1 + (1.0f - f1) * v1;
        s2 = f2 * s2 + (1.0f - f2) * v2;
        s3 = f3 * s3 + (1.0f - f3) * v3;
        a0 *= f0; a1 *= f1; a2 *= f2; a3 *= f3;
    }
    int o = ch * 8192 + bd;
    *(float4*)(Aa + o) = make_float4(a0, a1, a2, a3);
    *(float4*)(Ss + o) = make_float4(s0, s1, s2, s3);
}

// ---------------- Scan phase 2 (unchanged) ----------------
__global__ __launch_bounds__(256) void scan2_kernel(const float* __restrict__ Aa,
                                                    const float* __restrict__ Ss,
                                                    const float* __restrict__ c0,
                                                    float* __restrict__ cs,
                                                    float* __restrict__ lastc) {
    int bd = blockIdx.x * 256 + threadIdx.x;
    float c = c0[bd];
    #pragma unroll 4
    for (int ch = 0; ch < NCH; ++ch) {
        cs[ch * 8192 + bd] = c;
        c = Aa[ch * 8192 + bd] * c + Ss[ch * 8192 + bd];
    }
    lastc[bd] = c;
}

// ---------------- Scan phase 3: 4 chains/thread, float4 x/out (16B/lane) ----------------
__global__ __launch_bounds__(256) void scan3_kernel(const float* __restrict__ cs,
                                                    const u16* __restrict__ fg,
                                                    const u16* __restrict__ u,
                                                    const u16* __restrict__ rg,
                                                    const float2* __restrict__ mrs,
                                                    const float* __restrict__ gamma,
                                                    const float* __restrict__ beta,
                                                    const float* __restrict__ x,
                                                    float* __restrict__ out) {
    int ch = blockIdx.x;
    int bd = (blockIdx.y * 256 + threadIdx.x) * 4;
    int b = bd >> 10, d = bd & 1023;
    float4 gm = *(const float4*)(gamma + d);
    float4 bt = *(const float4*)(beta + d);
    float4 c4 = *(const float4*)(cs + ch * 8192 + bd);
    float c0v = c4.x, c1v = c4.y, c2v = c4.z, c3v = c4.w;
    for (int t = ch * CLEN; t < ch * CLEN + CLEN; ++t) {
        size_t idx = ((size_t)(t * B_DIM + b) << 10) + d;
        ushort4 f4 = *(const ushort4*)(fg + idx);
        ushort4 u4 = *(const ushort4*)(u + idx);
        ushort4 r4 = *(const ushort4*)(rg + idx);
        float4 x4 = *(const float4*)(x + idx);
        float2 mr = mrs[t * B_DIM + b];
        float f0 = bf2f(f4.x), f1 = bf2f(f4.y), f2 = bf2f(f4.z), f3 = bf2f(f4.w);
        float v0 = bf2f(u4.x), v1 = bf2f(u4.y), v2 = bf2f(u4.z), v3 = bf2f(u4.w);
        float r0 = bf2f(r4.x), r1 = bf2f(r4.y), r2 = bf2f(r4.z), r3 = bf2f(r4.w);
        float n0 = (x4.x - mr.x) * mr.y * gm.x + bt.x;
        float n1 = (x4.y - mr.x) * mr.y * gm.y + bt.y;
        float n2 = (x4.z - mr.x) * mr.y * gm.z + bt.z;
        float n3 = (x4.w - mr.x) * mr.y * gm.w + bt.w;
        c0v = f0 * c0v + (1.0f - f0) * v0;
        c1v = f1 * c1v + (1.0f - f1) * v1;
        c2v = f2 * c2v + (1.0f - f2) * v2;
        c3v = f3 * c3v + (1.0f - f3) * v3;
        float h0 = r0 * tanhf(c0v) + (1.0f - r0) * n0;
        float h1 = r1 * tanhf(c1v) + (1.0f - r1) * n1;
        float h2 = r2 * tanhf(c2v) + (1.0f - r2) * n2;
        float h3 = r3 * tanhf(c3v) + (1.0f - r3) * n3;
        *(float4*)(out + idx) = make_float4(x4.x + h0, x4.y + h1, x4.z + h2, x4.w + h3);
    }
}

extern "C" void kernel_launch(void* const* d_in, const int* in_sizes, int n_in,
                              void* d_out, int out_size, void* d_ws, size_t ws_size,
                              hipStream_t stream) {
    const float* x     = (const float*)d_in[0];
    const float* c0    = (const float*)d_in[1];
    const float* W     = (const float*)d_in[2];
    const float* b     = (const float*)d_in[3];
    const float* gamma = (const float*)d_in[4];
    const float* beta  = (const float*)d_in[5];
    float* out = (float*)d_out;
    float* lastc = out + (size_t)M_DIM * D_DIM;
    // fp8 A scratch in d_out[0:16MB]: written by lnwt, read by gemm_fused, overwritten
    // only by scan3 at the end (stream-serial, deterministic).
    u8* xq = (u8*)d_out;

    char* w = (char*)d_ws;
    u16* xn = (u16*)w;  w += (size_t)M_DIM * D_DIM * 2;
    u16* Wt = (u16*)w;  w += (size_t)N_DIM * K_DIM * 2;
    u16* ug = (u16*)w;  w += (size_t)M_DIM * D_DIM * 2;
    u16* fg = (u16*)w;  w += (size_t)M_DIM * D_DIM * 2;
    u16* rg = (u16*)w;  w += (size_t)M_DIM * D_DIM * 2;
    float* Aa = (float*)w; w += (size_t)NCH * 8192 * 4;
    float* Ss = (float*)w; w += (size_t)NCH * 8192 * 4;
    float* cs = (float*)w; w += (size_t)NCH * 8192 * 4;
    float2* mrs = (float2*)w; w += (size_t)M_DIM * 8;
    u8* Wf8 = (u8*)w; w += (size_t)2048 * K_DIM;   // +2MB

    hipFuncSetAttribute(reinterpret_cast<const void*>(gemm_fused),
                        hipFuncAttributeMaxDynamicSharedMemorySize, LDS_TOTAL);

    lnwt_kernel<<<M_DIM + 768, 256, 0, stream>>>(x, gamma, beta, W, xn, xq, mrs, Wt, Wf8);
    gemm_fused<<<dim3(M_DIM / 256, 12), 512, LDS_TOTAL, stream>>>(xn, Wt, xq, Wf8, b, ug, fg, rg);
    scan1_kernel<<<dim3(NCH, 8), 256, 0, stream>>>(fg, ug, Aa, Ss);
    scan2_kernel<<<32, 256, 0, stream>>>(Aa, Ss, c0, cs, lastc);
    scan3_kernel<<<dim3(NCH, 8), 256, 0, stream>>>(cs, fg, ug, rg, mrs, gamma, beta, x, out);
}

// Round 16
// 195.424 us; speedup vs baseline: 1.0222x; 1.0222x over previous
//
#include <hip/hip_runtime.h>
#include <hip/hip_bf16.h>
#include <hip/hip_fp8.h>

// SRU layer: LN -> fused split GEMM (u: bf16 R7; f/r: fp8 e4m3 BK=128 k-interleaved,
// one dispatch, block-uniform branch) -> chunked scan.  L=2048, B=8, D=1024.
// Best verified configuration (R14: 195.8 us, absmax 0.125).

typedef unsigned short u16;
typedef unsigned char u8;
typedef __bf16 bf16x8 __attribute__((ext_vector_type(8)));
typedef float f32x4 __attribute__((ext_vector_type(4)));
typedef long longx2 __attribute__((ext_vector_type(2)));

#define L_DIM 2048
#define B_DIM 8
#define D_DIM 1024
#define M_DIM (L_DIM * B_DIM)   // 16384
#define K_DIM D_DIM             // 1024
#define N_DIM (3 * D_DIM)       // 3072
#define NCH 32
#define CLEN (L_DIM / NCH)      // 64
#define NT (K_DIM / 64)         // 16 bf16 K-tiles
#define NT8 (K_DIM / 128)       // 8 fp8 K-tiles

// Both paths: A dbuf 2x32K @0, B dbuf 2x32K @65536, dummy 16K @131072
#define LDS_B 65536
#define LDS_DUMMY 131072
#define LDS_TOTAL 147456

__device__ __forceinline__ float bf2f(u16 h) {
    unsigned int u = ((unsigned int)h) << 16;
    float f;
    __builtin_memcpy(&f, &u, 4);
    return f;
}

__device__ __forceinline__ u16 f2bf(float f) {
    unsigned int u;
    __builtin_memcpy(&u, &f, 4);
    u = u + 0x7fff + ((u >> 16) & 1);   // RNE
    return (u16)(u >> 16);
}

__device__ __forceinline__ u8 f2e4(float v) {
    __hip_fp8_e4m3 t(v);   // OCP e4m3fn, RNE
    return (u8)t.__x;
}

// fp8 k-interleave: within each 128B K-block, byte for k goes to
// pos = ((kk>>1)*4 + lg)*16 + (kk&1)*8 + e   (kk=k>>5, lg=(k>>3)&3, e=k&7)
__device__ __forceinline__ int kperm(int klocal) {
    int kk = klocal >> 5, lg = (klocal >> 3) & 3, e = klocal & 7;
    return (((kk >> 1) * 4 + lg) << 4) + ((kk & 1) << 3) + e;
}

__device__ __forceinline__ void async16(void* lds, const void* g) {
    __builtin_amdgcn_global_load_lds(
        (const __attribute__((address_space(1))) void*)g,
        (__attribute__((address_space(3))) void*)lds, 16, 0, 0);
}

// ---------------- LayerNorm: bf16 xn + fp8 xq (k-interleaved) + (mu,rs) ----------------
__global__ __launch_bounds__(256) void ln_kernel(const float* __restrict__ x,
                                                 const float* __restrict__ gamma,
                                                 const float* __restrict__ beta,
                                                 u16* __restrict__ xn,
                                                 u8* __restrict__ xq,
                                                 float2* __restrict__ mrs) {
    int row = blockIdx.x;
    int tid = threadIdx.x;
    const float4* xr = (const float4*)(x + (size_t)row * D_DIM);
    float4 v = xr[tid];
    float s = v.x + v.y + v.z + v.w;
    float q = v.x * v.x + v.y * v.y + v.z * v.z + v.w * v.w;
    #pragma unroll
    for (int off = 32; off; off >>= 1) {
        s += __shfl_down(s, off);
        q += __shfl_down(q, off);
    }
    __shared__ float ss[4], qq[4];
    int lane = tid & 63, wv = tid >> 6;
    if (lane == 0) { ss[wv] = s; qq[wv] = q; }
    __syncthreads();
    s = ss[0] + ss[1] + ss[2] + ss[3];
    q = qq[0] + qq[1] + qq[2] + qq[3];
    float mu = s * (1.0f / D_DIM);
    float var = q * (1.0f / D_DIM) - mu * mu;
    float rs = rsqrtf(var + 1e-5f);
    if (tid == 0) mrs[row] = make_float2(mu, rs);
    float4 g = ((const float4*)gamma)[tid];
    float4 bt = ((const float4*)beta)[tid];
    float n0 = (v.x - mu) * rs * g.x + bt.x;
    float n1 = (v.y - mu) * rs * g.y + bt.y;
    float n2 = (v.z - mu) * rs * g.z + bt.z;
    float n3 = (v.w - mu) * rs * g.w + bt.w;
    ushort4 o;
    o.x = f2bf(n0); o.y = f2bf(n1); o.z = f2bf(n2); o.w = f2bf(n3);
    ((ushort4*)(xn + (size_t)row * D_DIM))[tid] = o;
    uchar4 o8;
    o8.x = f2e4(n0); o8.y = f2e4(n1); o8.z = f2e4(n2); o8.w = f2e4(n3);
    int k4 = tid * 4;
    int pos = (k4 & ~127) + kperm(k4 & 127);   // 4B-aligned (e in {0,4})
    *(uchar4*)(xq + (size_t)row * D_DIM + pos) = o8;
}

// ---------------- W prep: n<1024 -> Wt bf16; n>=1024 -> Wf8 fp8*64 k-interleaved ------
__global__ __launch_bounds__(256) void wt_kernel(const float* __restrict__ W,
                                                 u16* __restrict__ Wt,
                                                 u8* __restrict__ Wf8) {
    __shared__ float t[64][65];
    int k0 = blockIdx.x * 64;
    int n0 = blockIdx.y * 64;
    int col = threadIdx.x & 63;
    int rg4 = threadIdx.x >> 6;
    #pragma unroll
    for (int j = 0; j < 16; ++j) {
        int r = rg4 * 16 + j;
        t[r][col] = W[(size_t)(k0 + r) * N_DIM + n0 + col];
    }
    __syncthreads();
    if (n0 < 1024) {
        #pragma unroll
        for (int j = 0; j < 16; ++j) {
            int nr = rg4 * 16 + j;
            Wt[(size_t)(n0 + nr) * K_DIM + k0 + col] = f2bf(t[col][nr]);
        }
    } else {
        #pragma unroll
        for (int j = 0; j < 16; ++j) {
            int nr = rg4 * 16 + j;
            int k = k0 + col;
            int pos = (k & ~127) + kperm(k & 127);
            Wf8[(size_t)(n0 - 1024 + nr) * K_DIM + pos] = f2e4(t[col][nr] * 64.0f);
        }
    }
}

// ---------------- Fused GEMM: grid (64,12). y<4: bf16 u-path; y>=4: fp8 f/r-path ------
// Both paths are R12's kernels verbatim (identical LDS plan, 512 thr, 8 waves 2Mx4N,
// 8-phase counted-vmcnt(4), both-sides ^(row&7) swizzle). Fusion overlaps gemm_u's
// tail drain with gemm8's prologue (CU picks up an fp8 block as its bf16 block ends).
__global__ __launch_bounds__(512, 2) void gemm_fused(const u16* __restrict__ A,
                                                     const u16* __restrict__ Bt,
                                                     const u8* __restrict__ A8,
                                                     const u8* __restrict__ B8,
                                                     const float* __restrict__ bias,
                                                     u16* __restrict__ uo,
                                                     u16* __restrict__ fo,
                                                     u16* __restrict__ ro) {
    extern __shared__ char lds[];
    const int tid = threadIdx.x;
    const int wave = tid >> 6, lane = tid & 63;
    const int lm = lane & 15, lg = lane >> 4;
    const int wm = wave >> 2, wn = wave & 3;   // 2M x 4N
    const int m0 = blockIdx.x * 256;

#define PH_SYNC()                                                               \
    do { __builtin_amdgcn_s_barrier();                                          \
         asm volatile("s_waitcnt lgkmcnt(0)");                                  \
         __builtin_amdgcn_sched_barrier(0); } while (0)

    if (blockIdx.y < 4) {
        // ================= bf16 u-path (R7/R12 verbatim) =================
        const int n0 = blockIdx.y * 256;       // < 1024

        const int xk0 = ((0 | lg) ^ (lm & 7)) << 4;
        const int xk1 = ((4 | lg) ^ (lm & 7)) << 4;
        const char* pA0 = lds + (wm * 128 + lm) * 128 + xk0;
        const char* pA1 = lds + (wm * 128 + lm) * 128 + xk1;
        const char* pB0 = lds + LDS_B + (wn * 64 + lm) * 128 + xk0;
        const char* pB1 = lds + LDS_B + (wn * 64 + lm) * 128 + xk1;

        const int c1 = 512 + tid;
        const int r0 = tid >> 3, cc0 = (tid & 7) ^ (r0 & 7);
        const int r1 = c1 >> 3, cc1 = (c1 & 7) ^ (r1 & 7);
        const char* gA0 = (const char*)A + ((size_t)(m0 + r0) * K_DIM + cc0 * 8) * 2;
        const char* gA1 = (const char*)A + ((size_t)(m0 + r1) * K_DIM + cc1 * 8) * 2;
        const char* gB0 = (const char*)Bt + ((size_t)(n0 + r0) * K_DIM + cc0 * 8) * 2;
        const char* gB1 = (const char*)Bt + ((size_t)(n0 + r1) * K_DIM + cc1 * 8) * 2;
        char* dstW = lds + wave * 1024;

        f32x4 acc[8][4] = {};
        bf16x8 av[4], aw[4], bv0[4], bv1[4];

        auto stageA = [&](int t1, int h) {
            char* dst = (t1 < NT) ? (dstW + ((t1 & 1) << 15) + (h << 14))
                                  : (lds + LDS_DUMMY + wave * 1024);
            int ko = ((t1 & 15) << 7) + (h << 18);
            async16(dst,        gA0 + ko);
            async16(dst + 8192, gA1 + ko);
        };
        auto stageB = [&](int t2, int h) {
            char* dst = (t2 < NT) ? (dstW + LDS_B + ((t2 & 1) << 15) + (h << 14))
                                  : (lds + LDS_DUMMY + wave * 1024);
            int ko = ((t2 & 15) << 7) + (h << 18);
            async16(dst,        gB0 + ko);
            async16(dst + 8192, gB1 + ko);
        };

#define LDA(dst, pbase, bb, mf0)                                                \
    do { _Pragma("unroll")                                                      \
        for (int q = 0; q < 4; ++q)                                             \
            dst[q] = *(const bf16x8*)(pbase + (bb) * 32768 + ((mf0) + q) * 2048); \
    } while (0)

#define LDB(dst, pbase, bb)                                                     \
    do { _Pragma("unroll")                                                      \
        for (int nf = 0; nf < 4; ++nf)                                          \
            dst[nf] = *(const bf16x8*)(pbase + (bb) * 32768 + nf * 2048);       \
    } while (0)

#define MFMA16(r0q, afr, bfr)                                                   \
    do { _Pragma("unroll")                                                      \
        for (int q = 0; q < 4; ++q)                                             \
            _Pragma("unroll")                                                   \
            for (int nf = 0; nf < 4; ++nf)                                      \
                acc[(r0q) + q][nf] = __builtin_amdgcn_mfma_f32_16x16x32_bf16(   \
                    afr[q], bfr[nf], acc[(r0q) + q][nf], 0, 0, 0);              \
    } while (0)

#define TILE_BODY(t, bb)                                                        \
    do {                                                                        \
        LDA(av, pA0, bb, 0);                                                    \
        LDB(bv0, pB0, bb);                                                      \
        stageA((t) + 1, 0);                                                     \
        PH_SYNC();                                                              \
        __builtin_amdgcn_s_setprio(1);  MFMA16(0, av, bv0);                     \
        __builtin_amdgcn_s_setprio(0);  __builtin_amdgcn_s_barrier();           \
        LDA(av, pA1, bb, 0);                                                    \
        LDB(bv1, pB1, bb);                                                      \
        stageA((t) + 1, 1);                                                     \
        PH_SYNC();                                                              \
        __builtin_amdgcn_s_setprio(1);  MFMA16(0, av, bv1);                     \
        __builtin_amdgcn_s_setprio(0);  __builtin_amdgcn_s_barrier();           \
        LDA(aw, pA0, bb, 4);                                                    \
        stageB((t) + 2, 0);                                                     \
        PH_SYNC();                                                              \
        __builtin_amdgcn_s_setprio(1);  MFMA16(4, aw, bv0);                     \
        __builtin_amdgcn_s_setprio(0);  __builtin_amdgcn_s_barrier();           \
        LDA(aw, pA1, bb, 4);                                                    \
        stageB((t) + 2, 1);                                                     \
        PH_SYNC();                                                              \
        __builtin_amdgcn_s_setprio(1);  MFMA16(4, aw, bv1);                     \
        __builtin_amdgcn_s_setprio(0);                                          \
        asm volatile("s_waitcnt vmcnt(4)" ::: "memory");                        \
        __builtin_amdgcn_s_barrier();                                           \
    } while (0)

        stageA(0, 0); stageA(0, 1);
        stageB(0, 0); stageB(0, 1);
        stageB(1, 0); stageB(1, 1);
        asm volatile("s_waitcnt vmcnt(4)" ::: "memory");
        __builtin_amdgcn_s_barrier();

        for (int t = 0; t < NT; t += 2) {
            TILE_BODY(t, 0);
            TILE_BODY(t + 1, 1);
        }

        float bb4[4];
        #pragma unroll
        for (int nf = 0; nf < 4; ++nf) bb4[nf] = bias[n0 + wn * 64 + nf * 16 + lm];
        const int cmb = n0 + wn * 64 + lm;
        #pragma unroll
        for (int mf = 0; mf < 8; ++mf) {
            #pragma unroll
            for (int j = 0; j < 4; ++j) {
                int row = m0 + wm * 128 + mf * 16 + lg * 4 + j;
                u16* rp = uo + (size_t)row * D_DIM + cmb;
                #pragma unroll
                for (int nf = 0; nf < 4; ++nf)
                    rp[nf * 16] = f2bf(acc[mf][nf][j] + bb4[nf]);
            }
        }
#undef LDA
#undef LDB
#undef MFMA16
#undef TILE_BODY
    } else {
        // ================= fp8 f/r-path (R12 verbatim) =================
        const int n0 = (blockIdx.y - 4) * 256;   // 0..2047 (f,r cols)

        const int xj0 = (((0 * 4 + lg) ^ (lm & 7)) << 4);   // kk-pair a=0
        const int xj1 = (((1 * 4 + lg) ^ (lm & 7)) << 4);   // kk-pair a=1
        const char* pA = lds + (wm * 128 + lm) * 128;
        const char* pB = lds + LDS_B + (wn * 64 + lm) * 128;

        const int c1 = 512 + tid;
        const int r0 = tid >> 3, cc0 = (tid & 7) ^ (r0 & 7);
        const int r1 = c1 >> 3, cc1 = (c1 & 7) ^ (r1 & 7);
        const char* gA0 = (const char*)A8 + (size_t)(m0 + r0) * K_DIM + cc0 * 16;
        const char* gA1 = (const char*)A8 + (size_t)(m0 + r1) * K_DIM + cc1 * 16;
        const char* gB0 = (const char*)B8 + (size_t)(n0 + r0) * K_DIM + cc0 * 16;
        const char* gB1 = (const char*)B8 + (size_t)(n0 + r1) * K_DIM + cc1 * 16;
        char* dstW = lds + wave * 1024;

        f32x4 acc[8][4] = {};
        longx2 av[8], bv01[4], bv23[4];

        auto stageA8 = [&](int t1, int h) {
            char* dst = (t1 < NT8) ? (dstW + ((t1 & 1) << 15) + (h << 14))
                                   : (lds + LDS_DUMMY + wave * 1024);
            int ko = ((t1 & 7) << 7) + (h << 17);
            async16(dst,        gA0 + ko);
            async16(dst + 8192, gA1 + ko);
        };
        auto stageB8 = [&](int t2, int h) {
            char* dst = (t2 < NT8) ? (dstW + LDS_B + ((t2 & 1) << 15) + (h << 14))
                                   : (lds + LDS_DUMMY + wave * 1024);
            int ko = ((t2 & 7) << 7) + (h << 17);
            async16(dst,        gB0 + ko);
            async16(dst + 8192, gB1 + ko);
        };

#define LDA8(xj, bb)                                                            \
    do { _Pragma("unroll")                                                      \
        for (int q = 0; q < 8; ++q)                                             \
            av[q] = *(const longx2*)(pA + (bb) * 32768 + q * 2048 + (xj));      \
    } while (0)

#define LDB8(dst, xj, bb)                                                       \
    do { _Pragma("unroll")                                                      \
        for (int nf = 0; nf < 4; ++nf)                                          \
            dst[nf] = *(const longx2*)(pB + (bb) * 32768 + nf * 2048 + (xj));   \
    } while (0)

#define MFMA32F8(bfr, h)                                                        \
    do { _Pragma("unroll")                                                      \
        for (int q = 0; q < 8; ++q)                                             \
            _Pragma("unroll")                                                   \
            for (int nf = 0; nf < 4; ++nf)                                      \
                acc[q][nf] = __builtin_amdgcn_mfma_f32_16x16x32_fp8_fp8(        \
                    av[q][h], bfr[nf][h], acc[q][nf], 0, 0, 0);                 \
    } while (0)

#define TILE_BODY8(t, bb)                                                       \
    do {                                                                        \
        LDA8(xj0, bb);                                                          \
        LDB8(bv01, xj0, bb);                                                    \
        stageA8((t) + 1, 0);                                                    \
        PH_SYNC();                                                              \
        __builtin_amdgcn_s_setprio(1);  MFMA32F8(bv01, 0);                      \
        __builtin_amdgcn_s_setprio(0);  __builtin_amdgcn_s_barrier();           \
        LDB8(bv23, xj1, bb);                                                    \
        stageA8((t) + 1, 1);                                                    \
        PH_SYNC();                                                              \
        __builtin_amdgcn_s_setprio(1);  MFMA32F8(bv01, 1);                      \
        __builtin_amdgcn_s_setprio(0);  __builtin_amdgcn_s_barrier();           \
        LDA8(xj1, bb);                                                          \
        stageB8((t) + 2, 0);                                                    \
        PH_SYNC();                                                              \
        __builtin_amdgcn_s_setprio(1);  MFMA32F8(bv23, 0);                      \
        __builtin_amdgcn_s_setprio(0);  __builtin_amdgcn_s_barrier();           \
        stageB8((t) + 2, 1);                                                    \
        __builtin_amdgcn_s_barrier();                                           \
        __builtin_amdgcn_s_setprio(1);  MFMA32F8(bv23, 1);                      \
        __builtin_amdgcn_s_setprio(0);                                          \
        asm volatile("s_waitcnt vmcnt(4)" ::: "memory");                        \
        __builtin_amdgcn_s_barrier();                                           \
    } while (0)

        stageA8(0, 0); stageA8(0, 1);
        stageB8(0, 0); stageB8(0, 1);
        stageB8(1, 0); stageB8(1, 1);
        asm volatile("s_waitcnt vmcnt(4)" ::: "memory");
        __builtin_amdgcn_s_barrier();

        for (int t = 0; t < NT8; t += 2) {
            TILE_BODY8(t, 0);
            TILE_BODY8(t + 1, 1);
        }

        int seg = n0 >> 10;   // 0 -> f, 1 -> r (block-uniform)
        u16* outp = seg ? ro : fo;
        float bb4[4];
        #pragma unroll
        for (int nf = 0; nf < 4; ++nf) bb4[nf] = bias[1024 + n0 + wn * 64 + nf * 16 + lm];
        const int cmb = (n0 + wn * 64 + lm) & 1023;
        #pragma unroll
        for (int mf = 0; mf < 8; ++mf) {
            #pragma unroll
            for (int j = 0; j < 4; ++j) {
                int row = m0 + wm * 128 + mf * 16 + lg * 4 + j;
                u16* rp = outp + (size_t)row * D_DIM + cmb;
                #pragma unroll
                for (int nf = 0; nf < 4; ++nf) {
                    float val = acc[mf][nf][j] * 0.015625f + bb4[nf];
                    rp[nf * 16] = f2bf(1.0f / (1.0f + __expf(-val)));
                }
            }
        }
#undef LDA8
#undef LDB8
#undef MFMA32F8
#undef TILE_BODY8
    }
#undef PH_SYNC
}

// ---------------- Scan phase 1 ----------------
__global__ __launch_bounds__(256) void scan1_kernel(const u16* __restrict__ fg,
                                                    const u16* __restrict__ u,
                                                    float* __restrict__ Aa,
                                                    float* __restrict__ Ss) {
    int ch = blockIdx.x;
    int bd = (blockIdx.y * 256 + threadIdx.x) * 2;
    int b = bd >> 10, d = bd & 1023;
    float a0 = 1.0f, a1 = 1.0f, s0 = 0.0f, s1 = 0.0f;
    for (int t = ch * CLEN; t < ch * CLEN + CLEN; ++t) {
        size_t idx = ((size_t)(t * B_DIM + b) << 10) + d;
        ushort2 f2 = *(const ushort2*)(fg + idx);
        ushort2 u2 = *(const ushort2*)(u + idx);
        float f0 = bf2f(f2.x), f1 = bf2f(f2.y);
        float v0 = bf2f(u2.x), v1 = bf2f(u2.y);
        s0 = f0 * s0 + (1.0f - f0) * v0;
        s1 = f1 * s1 + (1.0f - f1) * v1;
        a0 *= f0;
        a1 *= f1;
    }
    int o = ch * 8192 + bd;
    *(float2*)(Aa + o) = make_float2(a0, a1);
    *(float2*)(Ss + o) = make_float2(s0, s1);
}

// ---------------- Scan phase 2 ----------------
__global__ __launch_bounds__(256) void scan2_kernel(const float* __restrict__ Aa,
                                                    const float* __restrict__ Ss,
                                                    const float* __restrict__ c0,
                                                    float* __restrict__ cs,
                                                    float* __restrict__ lastc) {
    int bd = blockIdx.x * 256 + threadIdx.x;
    float c = c0[bd];
    #pragma unroll 4
    for (int ch = 0; ch < NCH; ++ch) {
        cs[ch * 8192 + bd] = c;
        c = Aa[ch * 8192 + bd] * c + Ss[ch * 8192 + bd];
    }
    lastc[bd] = c;
}

// ---------------- Scan phase 3: replay + recompute x_norm from x ----------------
__global__ __launch_bounds__(256) void scan3_kernel(const float* __restrict__ cs,
                                                    const u16* __restrict__ fg,
                                                    const u16* __restrict__ u,
                                                    const u16* __restrict__ rg,
                                                    const float2* __restrict__ mrs,
                                                    const float* __restrict__ gamma,
                                                    const float* __restrict__ beta,
                                                    const float* __restrict__ x,
                                                    float* __restrict__ out) {
    int ch = blockIdx.x;
    int bd = (blockIdx.y * 256 + threadIdx.x) * 2;
    int b = bd >> 10, d = bd & 1023;
    float2 gm = *(const float2*)(gamma + d);
    float2 bt = *(const float2*)(beta + d);
    float c0v = cs[ch * 8192 + bd];
    float c1v = cs[ch * 8192 + bd + 1];
    for (int t = ch * CLEN; t < ch * CLEN + CLEN; ++t) {
        size_t idx = ((size_t)(t * B_DIM + b) << 10) + d;
        ushort2 f2 = *(const ushort2*)(fg + idx);
        ushort2 u2 = *(const ushort2*)(u + idx);
        ushort2 r2 = *(const ushort2*)(rg + idx);
        float2 x2 = *(const float2*)(x + idx);
        float2 mr = mrs[t * B_DIM + b];
        float f0 = bf2f(f2.x), f1 = bf2f(f2.y);
        float v0 = bf2f(u2.x), v1 = bf2f(u2.y);
        float r0 = bf2f(r2.x), r1 = bf2f(r2.y);
        float n0 = (x2.x - mr.x) * mr.y * gm.x + bt.x;
        float n1 = (x2.y - mr.x) * mr.y * gm.y + bt.y;
        c0v = f0 * c0v + (1.0f - f0) * v0;
        c1v = f1 * c1v + (1.0f - f1) * v1;
        float h0 = r0 * tanhf(c0v) + (1.0f - r0) * n0;
        float h1 = r1 * tanhf(c1v) + (1.0f - r1) * n1;
        *(float2*)(out + idx) = make_float2(x2.x + h0, x2.y + h1);
    }
}

extern "C" void kernel_launch(void* const* d_in, const int* in_sizes, int n_in,
                              void* d_out, int out_size, void* d_ws, size_t ws_size,
                              hipStream_t stream) {
    const float* x     = (const float*)d_in[0];
    const float* c0    = (const float*)d_in[1];
    const float* W     = (const float*)d_in[2];
    const float* b     = (const float*)d_in[3];
    const float* gamma = (const float*)d_in[4];
    const float* beta  = (const float*)d_in[5];
    float* out = (float*)d_out;
    float* lastc = out + (size_t)M_DIM * D_DIM;
    // fp8 A scratch in d_out[0:16MB]: written by ln, read by gemm_fused, overwritten
    // only by scan3 at the end (stream-serial, deterministic).
    u8* xq = (u8*)d_out;

    char* w = (char*)d_ws;
    u16* xn = (u16*)w;  w += (size_t)M_DIM * D_DIM * 2;
    u16* Wt = (u16*)w;  w += (size_t)N_DIM * K_DIM * 2;
    u16* ug = (u16*)w;  w += (size_t)M_DIM * D_DIM * 2;
    u16* fg = (u16*)w;  w += (size_t)M_DIM * D_DIM * 2;
    u16* rg = (u16*)w;  w += (size_t)M_DIM * D_DIM * 2;
    float* Aa = (float*)w; w += (size_t)NCH * 8192 * 4;
    float* Ss = (float*)w; w += (size_t)NCH * 8192 * 4;
    float* cs = (float*)w; w += (size_t)NCH * 8192 * 4;
    float2* mrs = (float2*)w; w += (size_t)M_DIM * 8;
    u8* Wf8 = (u8*)w; w += (size_t)2048 * K_DIM;   // +2MB

    hipFuncSetAttribute(reinterpret_cast<const void*>(gemm_fused),
                        hipFuncAttributeMaxDynamicSharedMemorySize, LDS_TOTAL);

    ln_kernel<<<M_DIM, 256, 0, stream>>>(x, gamma, beta, xn, xq, mrs);
    wt_kernel<<<dim3(K_DIM / 64, N_DIM / 64), 256, 0, stream>>>(W, Wt, Wf8);
    gemm_fused<<<dim3(M_DIM / 256, 12), 512, LDS_TOTAL, stream>>>(xn, Wt, xq, Wf8, b, ug, fg, rg);
    scan1_kernel<<<dim3(NCH, 16), 256, 0, stream>>>(fg, ug, Aa, Ss);
    scan2_kernel<<<32, 256, 0, stream>>>(Aa, Ss, c0, cs, lastc);
    scan3_kernel<<<dim3(NCH, 16), 256, 0, stream>>>(cs, fg, ug, rg, mrs, gamma, beta, x, out);
}